// Round 3
// baseline (189.619 us; speedup 1.0000x reference)
//
#include <hip/hip_runtime.h>
#include <hip/hip_bf16.h>

// SO3TensorProductLayer: out = relu(128*(x (x) x) @ W1 + b1) @ W2 + b2
// h[c][b] = 128 * sum_i x[b,i] * (sum_j W1T[c][i*128+j] * x[b,j])
// gemm1 v6: occupancy-quantum push. Post-mortem v5: regs 152 vs v3's 192
// BOTH land in the (128,256] HW allocation bucket -> 2 waves/SIMD (m69
// quantum at 64/128/256); occupancy never moved (19->20%) and halved
// per-wave work doubled prologue overhead -> 85->100us regression.
// v6 crosses the 128 boundary: wave tile c16 x b64 (tn=4), regs
// ~ acc16(AGPR) + Xf32 + A16 + misc ~= 100-110 total, launch_bounds
// (256,4) pins the 128 cap -> 4 waves/SIMD. Block c64 x b64 (4 waves on
// c), grid (64,8,4)=2048. A-chunk still feeds 8 MFMAs (chained ks pair);
// L2 A-traffic 1.07GB ~ well under 34.5TB/s ceiling.
// CORRECTNESS DISCIPLINE: v5-proven scalarized shape (named A00/A01/
// A10/A11, zero runtime-indexed vector arrays); only tile size + cap
// changed. If wrong -> the cap miscompiles -> revert to round-0 v3.
// Partials bf16 [z][b][c] (r4-proven).

typedef __attribute__((ext_vector_type(8))) short short8;   // 8 bf16
typedef __attribute__((ext_vector_type(4))) float floatx4;  // 4 fp32

__device__ __forceinline__ unsigned short f2bf(float f) {
    union { float f; unsigned int u; } v; v.f = f;
    unsigned int r = v.u + 0x7fffu + ((v.u >> 16) & 1u);   // RNE
    return (unsigned short)(r >> 16);
}
__device__ __forceinline__ float bf2f(unsigned short b) {
    union { unsigned int u; float f; } v; v.u = ((unsigned int)b) << 16;
    return v.f;
}

// ---------------------------------------------------------------------------
// Pack W1 [16384 K][512 C] fp32 -> W1Tp chunks of 1KB: chunk(c16,kc) holds
// A-fragment for c rows c16*16..+15, K cols kc*32..+31: wave load at
// (chunkBase + lane*16B) gives lane(m=lane&15,quad=lane>>4) the 8 bf16 of
// W1[K=kc*32+quad*8+j][c=c16*16+m].
__global__ __launch_bounds__(256) void pack_w1_kernel(
    const float* __restrict__ W1, unsigned short* __restrict__ W1Tp) {
    __shared__ float tile[64][65];
    const int k0 = blockIdx.x * 64;
    const int c0 = blockIdx.y * 64;
    const int tr = threadIdx.x >> 4;
    const int tc4 = (threadIdx.x & 15) * 4;
#pragma unroll
    for (int p = 0; p < 4; ++p) {
        int k = p * 16 + tr;
        float4 v = *(const float4*)(W1 + (long)(k0 + k) * 512 + c0 + tc4);
        tile[k][tc4 + 0] = v.x; tile[k][tc4 + 1] = v.y;
        tile[k][tc4 + 2] = v.z; tile[k][tc4 + 3] = v.w;
    }
    __syncthreads();
    const int lane = threadIdx.x & 63;
    const int w = threadIdx.x >> 6;
    const int m = lane & 15, quad = lane >> 4;
#pragma unroll
    for (int pass = 0; pass < 2; ++pass) {
        int chunk = w * 2 + pass;              // 0..7
        int kcL = chunk & 1, c16L = chunk >> 1;
        union { unsigned short s[8]; uint4 u; } o;
#pragma unroll
        for (int j = 0; j < 8; ++j)
            o.s[j] = f2bf(tile[kcL * 32 + quad * 8 + j][c16L * 16 + m]);
        long c16g = (c0 >> 4) + c16L;
        long kcg  = (k0 >> 5) + kcL;
        *(uint4*)(W1Tp + (c16g * 512 + kcg) * 512 + lane * 8) = o.u;
    }
}

// in: [R][C] fp32 -> out: [C][R] bf16 (for W2 -> W2T).
__global__ __launch_bounds__(256) void transpose_cast_kernel(
    const float* __restrict__ in, unsigned short* __restrict__ out, int R, int C) {
    __shared__ float tile[64][65];
    const int r0 = blockIdx.x * 64, c0 = blockIdx.y * 64;
    const int tr = threadIdx.x >> 4;
    const int tc4 = (threadIdx.x & 15) * 4;
#pragma unroll
    for (int p = 0; p < 4; ++p) {
        int r = p * 16 + tr;
        float4 v = *(const float4*)(in + (long)(r0 + r) * C + c0 + tc4);
        tile[r][tc4 + 0] = v.x; tile[r][tc4 + 1] = v.y;
        tile[r][tc4 + 2] = v.z; tile[r][tc4 + 3] = v.w;
    }
    __syncthreads();
#pragma unroll
    for (int p = 0; p < 4; ++p) {
        int c = p * 16 + tr;
        union { unsigned short s[4]; uint2 u; } pk;
#pragma unroll
        for (int e = 0; e < 4; ++e) pk.s[e] = f2bf(tile[tc4 + e][c]);
        *(uint2*)(out + (long)(c0 + c) * R + r0 + tc4) = pk.u;
    }
}

// ---------------------------------------------------------------------------
// gemm1 v6: Pb[z][b][c] (bf16) over i-chunk z. 256 thr = 4 waves stacked on
// c (wid = c16 offset); wave tile c16 x b64 (tm=1, tn=4); block c64 x b64.
// grid (64 b, 8 c, 4 z) = 2048 blocks, b fastest.
__global__ __launch_bounds__(256, 4) void gemm1_kernel(
    const float* __restrict__ x,               // [4096][128]
    const unsigned short* __restrict__ W1Tp,
    unsigned short* __restrict__ Pb) {         // [4][4096][512] bf16
    __shared__ float xT[64][33];               // [b_local][i_local]
    const int tid = threadIdx.x;
    const int b0 = blockIdx.x * 64;
    const int c0 = blockIdx.y * 64;
    const int zi = blockIdx.z;
    const int i0 = zi * 32;

    // stage xT[b][i], coalesced global reads (8 floats per thread)
    for (int idx = tid; idx < 64 * 32; idx += 256) {
        int bL = idx >> 5, iL = idx & 31;
        xT[bL][iL] = x[(long)(b0 + bL) * 128 + i0 + iL];
    }
    __syncthreads();

    const int wid = tid >> 6;                  // 0..3 -> c16 offset
    const int lane = tid & 63;
    const int n16 = lane & 15, quad = lane >> 4;
    const int c16 = (c0 >> 4) + wid;

    floatx4 acc[4];
#pragma unroll
    for (int tn = 0; tn < 4; ++tn) acc[tn] = (floatx4){0.f, 0.f, 0.f, 0.f};
    const floatx4 zero4 = (floatx4){0.f, 0.f, 0.f, 0.f};

#pragma unroll
    for (int jh = 0; jh < 2; ++jh) {
        // x B-fragments, register-resident for this j-half (32 VGPRs)
        short8 Xf[2][4];
#pragma unroll
        for (int ks = 0; ks < 2; ++ks)
#pragma unroll
            for (int tn = 0; tn < 4; ++tn) {
                const float* xp = x + (long)(b0 + tn * 16 + n16) * 128
                                    + jh * 64 + ks * 32 + quad * 8;
                float4 v0 = *(const float4*)xp;
                float4 v1 = *(const float4*)(xp + 4);
                short8 f;
                f[0] = (short)f2bf(v0.x); f[1] = (short)f2bf(v0.y);
                f[2] = (short)f2bf(v0.z); f[3] = (short)f2bf(v0.w);
                f[4] = (short)f2bf(v1.x); f[5] = (short)f2bf(v1.y);
                f[6] = (short)f2bf(v1.z); f[7] = (short)f2bf(v1.w);
                Xf[ks][tn] = f;
            }
        // A chunk base pointers; ks stride = 1 chunk = 512 u16,
        // per-i advance = 4 chunks = 2048 u16
        const unsigned short* aB0 = W1Tp
            + ((long)c16 * 512 + (long)i0 * 4 + jh * 2) * 512 + lane * 8;
        const unsigned short* aB1 = aB0 + 512;

        // depth-2 ring, fully scalarized (no runtime-indexed vector arrays)
        short8 A00 = *(const short8*)(aB0);
        short8 A01 = *(const short8*)(aB1);
        short8 A10 = *(const short8*)(aB0 + 2048);
        short8 A11 = *(const short8*)(aB1 + 2048);

#pragma unroll 2
        for (int ib = 0; ib < 16; ++ib) {
            const int i = ib * 2;
            {   // even step: stage 0
                float xi[4];                   // scalarized under unroll
#pragma unroll
                for (int tn = 0; tn < 4; ++tn)
                    xi[tn] = xT[n16 + tn * 16][i];
#pragma unroll
                for (int tn = 0; tn < 4; ++tn) {
                    floatx4 t = __builtin_amdgcn_mfma_f32_16x16x32_bf16(
                        A00, Xf[0][tn], zero4, 0, 0, 0);
                    t = __builtin_amdgcn_mfma_f32_16x16x32_bf16(
                        A01, Xf[1][tn], t, 0, 0, 0);
                    acc[tn] += xi[tn] * t;
                }
                const int p = (i + 2) & 31;    // wrap: tail reload harmless
                A00 = *(const short8*)(aB0 + (long)p * 2048);
                A01 = *(const short8*)(aB1 + (long)p * 2048);
            }
            {   // odd step: stage 1
                float xi[4];
#pragma unroll
                for (int tn = 0; tn < 4; ++tn)
                    xi[tn] = xT[n16 + tn * 16][i + 1];
#pragma unroll
                for (int tn = 0; tn < 4; ++tn) {
                    floatx4 t = __builtin_amdgcn_mfma_f32_16x16x32_bf16(
                        A10, Xf[0][tn], zero4, 0, 0, 0);
                    t = __builtin_amdgcn_mfma_f32_16x16x32_bf16(
                        A11, Xf[1][tn], t, 0, 0, 0);
                    acc[tn] += xi[tn] * t;
                }
                const int p = (i + 3) & 31;
                A10 = *(const short8*)(aB0 + (long)p * 2048);
                A11 = *(const short8*)(aB1 + (long)p * 2048);
            }
        }
    }

    // store bf16 partial in [z][b][c]: per tn lane owns 4 c-consecutive
    unsigned short* pb = Pb + (long)zi * (4096L * 512);
#pragma unroll
    for (int tn = 0; tn < 4; ++tn) {
        int b = b0 + tn * 16 + n16;
        int cb = c16 * 16 + quad * 4;
        union { unsigned short s[4]; uint2 u; } pk;
#pragma unroll
        for (int r = 0; r < 4; ++r) pk.s[r] = f2bf(acc[tn][r]);
        *(uint2*)(pb + (long)b * 512 + cb) = pk.u;
    }
}

// ---------------------------------------------------------------------------
// tail: h[b][c] = relu(128*sum_z Pb[z][b][c] + b1[c]) (bf16, LDS), then
// out[b][o] = h @ W2T + b2. 256 thr = 4 waves; b-tile 16 (grid 256 blocks);
// each wave owns 64 o columns.
__global__ __launch_bounds__(256) void tail_kernel(
    const unsigned short* __restrict__ Pb,     // [4][4096][512] bf16
    const float* __restrict__ b1,              // [512]
    const unsigned short* __restrict__ W2T,    // [256][512] bf16
    const float* __restrict__ b2,              // [256]
    float* __restrict__ out) {                 // [4096][256]
    __shared__ unsigned short hL[16][516];
    __shared__ float b1s[512];
    const int tid = threadIdx.x;
    const int b0 = blockIdx.x * 16;
    b1s[tid] = b1[tid];
    b1s[tid + 256] = b1[tid + 256];
    __syncthreads();

    const unsigned int* Pu = (const unsigned int*)Pb;   // 2 bf16 per uint
#pragma unroll 4
    for (int idx = tid; idx < 16 * 256; idx += 256) {
        int bL = idx >> 8;                      // 0..15
        int cu = idx & 255;                     // uint index; c = 2*cu
        float s0 = 0.f, s1 = 0.f;
#pragma unroll
        for (int z = 0; z < 4; ++z) {
            unsigned int u = Pu[((long)z * 4096 + b0 + bL) * 256 + cu];
            s0 += bf2f((unsigned short)(u & 0xffff));
            s1 += bf2f((unsigned short)(u >> 16));
        }
        int c = cu * 2;
        float v0 = fmaxf(fmaf(128.f, s0, b1s[c]), 0.f);
        float v1 = fmaxf(fmaf(128.f, s1, b1s[c + 1]), 0.f);
        unsigned int pk = (unsigned int)f2bf(v0) | ((unsigned int)f2bf(v1) << 16);
        *(unsigned int*)&hL[bL][c] = pk;
    }
    __syncthreads();

    const int w = tid >> 6, lane = tid & 63;
    const int n16 = lane & 15, quad = lane >> 4;
    const int o0 = w * 64;
    floatx4 acc[4];
#pragma unroll
    for (int tn = 0; tn < 4; ++tn) acc[tn] = (floatx4){0.f, 0.f, 0.f, 0.f};

#pragma unroll 4
    for (int ks = 0; ks < 16; ++ks) {
        short8 Af, Bf[4];
        {
            const unsigned short* p = &hL[n16][ks * 32 + quad * 8];
            union { uint2 u[2]; short8 s; } cvt;
            cvt.u[0] = *(const uint2*)p;
            cvt.u[1] = *(const uint2*)(p + 4);
            Af = cvt.s;
        }
#pragma unroll
        for (int tn = 0; tn < 4; ++tn)
            Bf[tn] = *(const short8*)(W2T + (long)(o0 + tn * 16 + n16) * 512
                                      + ks * 32 + quad * 8);
#pragma unroll
        for (int tn = 0; tn < 4; ++tn)
            acc[tn] = __builtin_amdgcn_mfma_f32_16x16x32_bf16(
                Af, Bf[tn], acc[tn], 0, 0, 0);
    }
#pragma unroll
    for (int tn = 0; tn < 4; ++tn) {
        float bias = b2[o0 + tn * 16 + n16];
#pragma unroll
        for (int r = 0; r < 4; ++r)
            out[(long)(b0 + quad * 4 + r) * 256
                + o0 + tn * 16 + n16] = acc[tn][r] + bias;
    }
}

extern "C" void kernel_launch(void* const* d_in, const int* in_sizes, int n_in,
                              void* d_out, int out_size, void* d_ws, size_t ws_size,
                              hipStream_t stream) {
    const float* x  = (const float*)d_in[0];   // [4096,128]
    const float* W1 = (const float*)d_in[1];   // [16384,512]
    const float* b1 = (const float*)d_in[2];   // [512]
    const float* W2 = (const float*)d_in[3];   // [512,256]
    const float* b2 = (const float*)d_in[4];   // [256]
    float* out = (float*)d_out;                // [4096,256]

    char* ws = (char*)d_ws;
    unsigned short* W1Tp = (unsigned short*)(ws);                 // 16.78 MB
    unsigned short* W2T  = (unsigned short*)(ws + 16777216);      // 0.26 MB
    unsigned short* Pb   = (unsigned short*)(ws + 16777216 + 262144); // 16.78 MB bf16

    pack_w1_kernel<<<dim3(256, 8), 256, 0, stream>>>(W1, W1Tp);
    transpose_cast_kernel<<<dim3(8, 4), 256, 0, stream>>>(W2, W2T, 512, 256);
    gemm1_kernel<<<dim3(64, 8, 4), 256, 0, stream>>>(x, W1Tp, Pb);
    tail_kernel<<<dim3(256), 256, 0, stream>>>(Pb, b1, W2T, b2, out);
}

// Round 4
// 175.676 us; speedup vs baseline: 1.0794x; 1.0794x over previous
//
#include <hip/hip_runtime.h>
#include <hip/hip_bf16.h>

// SO3TensorProductLayer: out = relu(128*(x (x) x) @ W1 + b1) @ W2 + b2
// h[c][b] = 128 * sum_i x[b,i] * (sum_j W1T[c][i*128+j] * x[b,j])
// gemm1 v7: A-path latency fix on the proven v3 tiling (85us best).
// Post-mortem v6: occupancy 20->37% moved MfmaUtil NOT AT ALL (28%) ->
// limiter is per-step stall ~400-900cyc = A-load miss latency (FETCH
// 68-72MB vs 16.7MB resident W1Tp: every XCD re-fetches every slice).
// v7: (1) XCD swizzle: flat 512-block grid, L=(n&7)*64+(n>>3) -> all 16
// b-blocks of one (cy,z) A-slice on one XCD; 4 slices = 2MB < 4MB L2 ->
// A becomes L2-resident. (2) A-ring depth 4 (coverage ~3.5 steps) hides
// residual latency. Regs ~224 (160 VGPR + 64 acc), same 2-wave bucket as
// v3. Math byte-identical to round-0 passing kernel.
// REGALLOC (r5 lesson): no runtime-indexed vector arrays; named A regs.
// Partials bf16 [z][b][c] (r4-proven).

typedef __attribute__((ext_vector_type(8))) short short8;   // 8 bf16
typedef __attribute__((ext_vector_type(4))) float floatx4;  // 4 fp32

__device__ __forceinline__ unsigned short f2bf(float f) {
    union { float f; unsigned int u; } v; v.f = f;
    unsigned int r = v.u + 0x7fffu + ((v.u >> 16) & 1u);   // RNE
    return (unsigned short)(r >> 16);
}
__device__ __forceinline__ float bf2f(unsigned short b) {
    union { unsigned int u; float f; } v; v.u = ((unsigned int)b) << 16;
    return v.f;
}

// ---------------------------------------------------------------------------
// Pack W1 [16384 K][512 C] fp32 -> W1Tp chunks of 1KB: chunk(c16,kc) holds
// A-fragment for c rows c16*16..+15, K cols kc*32..+31: wave load at
// (chunkBase + lane*16B) gives lane(m=lane&15,quad=lane>>4) the 8 bf16 of
// W1[K=kc*32+quad*8+j][c=c16*16+m].
__global__ __launch_bounds__(256) void pack_w1_kernel(
    const float* __restrict__ W1, unsigned short* __restrict__ W1Tp) {
    __shared__ float tile[64][65];
    const int k0 = blockIdx.x * 64;
    const int c0 = blockIdx.y * 64;
    const int tr = threadIdx.x >> 4;
    const int tc4 = (threadIdx.x & 15) * 4;
#pragma unroll
    for (int p = 0; p < 4; ++p) {
        int k = p * 16 + tr;
        float4 v = *(const float4*)(W1 + (long)(k0 + k) * 512 + c0 + tc4);
        tile[k][tc4 + 0] = v.x; tile[k][tc4 + 1] = v.y;
        tile[k][tc4 + 2] = v.z; tile[k][tc4 + 3] = v.w;
    }
    __syncthreads();
    const int lane = threadIdx.x & 63;
    const int w = threadIdx.x >> 6;
    const int m = lane & 15, quad = lane >> 4;
#pragma unroll
    for (int pass = 0; pass < 2; ++pass) {
        int chunk = w * 2 + pass;              // 0..7
        int kcL = chunk & 1, c16L = chunk >> 1;
        union { unsigned short s[8]; uint4 u; } o;
#pragma unroll
        for (int j = 0; j < 8; ++j)
            o.s[j] = f2bf(tile[kcL * 32 + quad * 8 + j][c16L * 16 + m]);
        long c16g = (c0 >> 4) + c16L;
        long kcg  = (k0 >> 5) + kcL;
        *(uint4*)(W1Tp + (c16g * 512 + kcg) * 512 + lane * 8) = o.u;
    }
}

// in: [R][C] fp32 -> out: [C][R] bf16 (for W2 -> W2T).
__global__ __launch_bounds__(256) void transpose_cast_kernel(
    const float* __restrict__ in, unsigned short* __restrict__ out, int R, int C) {
    __shared__ float tile[64][65];
    const int r0 = blockIdx.x * 64, c0 = blockIdx.y * 64;
    const int tr = threadIdx.x >> 4;
    const int tc4 = (threadIdx.x & 15) * 4;
#pragma unroll
    for (int p = 0; p < 4; ++p) {
        int r = p * 16 + tr;
        float4 v = *(const float4*)(in + (long)(r0 + r) * C + c0 + tc4);
        tile[r][tc4 + 0] = v.x; tile[r][tc4 + 1] = v.y;
        tile[r][tc4 + 2] = v.z; tile[r][tc4 + 3] = v.w;
    }
    __syncthreads();
#pragma unroll
    for (int p = 0; p < 4; ++p) {
        int c = p * 16 + tr;
        union { unsigned short s[4]; uint2 u; } pk;
#pragma unroll
        for (int e = 0; e < 4; ++e) pk.s[e] = f2bf(tile[tc4 + e][c]);
        *(uint2*)(out + (long)(c0 + c) * R + r0 + tc4) = pk.u;
    }
}

// ---------------------------------------------------------------------------
// gemm1 v7: Pb[z][b][c] (bf16) over i-chunk z. 256 thr = 4 waves (2wm c x
// 2wn b); wave tile c32 x b128 (tm=2, tn=8); block tile c64 x b256.
// Flat grid 512; XCD swizzle: L=(n&7)*64+(n>>3); bx=L&15 cy=(L>>4)&7
// z=L>>7 -> all bx of one (cy,z) slice on one XCD (2MB/XCD, L2-resident).

// one i-step: use stage regs, fold, prefetch same stage for I+4
#define A_STEP(Ac00, Ac01, Ac10, Ac11, I)                                  \
    {                                                                      \
        float xi[8];                                                       \
        _Pragma("unroll")                                                  \
        for (int tn = 0; tn < 8; ++tn)                                     \
            xi[tn] = xT[bLloc + tn * 16][(I)];                             \
        _Pragma("unroll")                                                  \
        for (int tn = 0; tn < 8; ++tn) {                                   \
            floatx4 t0 = __builtin_amdgcn_mfma_f32_16x16x32_bf16(          \
                Ac00, Xf[0][tn], zero4, 0, 0, 0);                          \
            t0 = __builtin_amdgcn_mfma_f32_16x16x32_bf16(                  \
                Ac01, Xf[1][tn], t0, 0, 0, 0);                             \
            acc[0][tn] += xi[tn] * t0;                                     \
            floatx4 t1 = __builtin_amdgcn_mfma_f32_16x16x32_bf16(          \
                Ac10, Xf[0][tn], zero4, 0, 0, 0);                          \
            t1 = __builtin_amdgcn_mfma_f32_16x16x32_bf16(                  \
                Ac11, Xf[1][tn], t1, 0, 0, 0);                             \
            acc[1][tn] += xi[tn] * t1;                                     \
        }                                                                  \
        const int p_ = ((I) + 4) & 31; /* wrap: tail reload harmless */    \
        Ac00 = *(const short8*)(aB00 + (long)p_ * 2048);                   \
        Ac01 = *(const short8*)(aB01 + (long)p_ * 2048);                   \
        Ac10 = *(const short8*)(aB10 + (long)p_ * 2048);                   \
        Ac11 = *(const short8*)(aB11 + (long)p_ * 2048);                   \
    }

__global__ __launch_bounds__(256, 2) void gemm1_kernel(
    const float* __restrict__ x,               // [4096][128]
    const unsigned short* __restrict__ W1Tp,
    unsigned short* __restrict__ Pb) {         // [4][4096][512] bf16
    __shared__ float xT[256][34];              // [b_local][i_local]
    const int tid = threadIdx.x;
    // XCD-locality swizzle (bijective, 512 blocks, 8 XCDs)
    const int n = blockIdx.x;
    const int L = (n & 7) * 64 + (n >> 3);
    const int b0 = (L & 15) * 256;
    const int c0 = ((L >> 4) & 7) * 64;
    const int zi = L >> 7;
    const int i0 = zi * 32;

    // stage xT[b][i], coalesced global reads
    for (int idx = tid; idx < 256 * 32; idx += 256) {
        int bL = idx >> 5, iL = idx & 31;
        xT[bL][iL] = x[(long)(b0 + bL) * 128 + i0 + iL];
    }
    __syncthreads();

    const int wid = tid >> 6;
    const int wm = wid >> 1, wn = wid & 1;
    const int lane = tid & 63;
    const int n16 = lane & 15, quad = lane >> 4;
    const int bBase = b0 + wn * 128;
    const int c16base = (c0 >> 4) + wm * 2;
    const int bLloc = wn * 128 + n16;          // xT row for tn=0

    floatx4 acc[2][8];
#pragma unroll
    for (int tm = 0; tm < 2; ++tm)
#pragma unroll
        for (int tn = 0; tn < 8; ++tn) acc[tm][tn] = (floatx4){0.f, 0.f, 0.f, 0.f};
    const floatx4 zero4 = (floatx4){0.f, 0.f, 0.f, 0.f};

#pragma unroll
    for (int jh = 0; jh < 2; ++jh) {
        // x B-fragments, register-resident for this j-half (64 VGPRs)
        short8 Xf[2][8];
#pragma unroll
        for (int ks = 0; ks < 2; ++ks)
#pragma unroll
            for (int tn = 0; tn < 8; ++tn) {
                const float* xp = x + (long)(bBase + tn * 16 + n16) * 128
                                    + jh * 64 + ks * 32 + quad * 8;
                float4 v0 = *(const float4*)xp;
                float4 v1 = *(const float4*)(xp + 4);
                short8 f;
                f[0] = (short)f2bf(v0.x); f[1] = (short)f2bf(v0.y);
                f[2] = (short)f2bf(v0.z); f[3] = (short)f2bf(v0.w);
                f[4] = (short)f2bf(v1.x); f[5] = (short)f2bf(v1.y);
                f[6] = (short)f2bf(v1.z); f[7] = (short)f2bf(v1.w);
                Xf[ks][tn] = f;
            }
        // A chunk base pointers (scalarized); per-i advance = 2048 u16
        const unsigned short* aB00 = W1Tp
            + ((long)(c16base + 0) * 512 + (long)i0 * 4 + jh * 2 + 0) * 512
            + lane * 8;
        const unsigned short* aB01 = aB00 + 512;
        const unsigned short* aB10 = W1Tp
            + ((long)(c16base + 1) * 512 + (long)i0 * 4 + jh * 2 + 0) * 512
            + lane * 8;
        const unsigned short* aB11 = aB10 + 512;

        // depth-4 ring, fully scalarized (16 named short8)
        short8 A0_00 = *(const short8*)(aB00);
        short8 A0_01 = *(const short8*)(aB01);
        short8 A0_10 = *(const short8*)(aB10);
        short8 A0_11 = *(const short8*)(aB11);
        short8 A1_00 = *(const short8*)(aB00 + 1 * 2048);
        short8 A1_01 = *(const short8*)(aB01 + 1 * 2048);
        short8 A1_10 = *(const short8*)(aB10 + 1 * 2048);
        short8 A1_11 = *(const short8*)(aB11 + 1 * 2048);
        short8 A2_00 = *(const short8*)(aB00 + 2 * 2048);
        short8 A2_01 = *(const short8*)(aB01 + 2 * 2048);
        short8 A2_10 = *(const short8*)(aB10 + 2 * 2048);
        short8 A2_11 = *(const short8*)(aB11 + 2 * 2048);
        short8 A3_00 = *(const short8*)(aB00 + 3 * 2048);
        short8 A3_01 = *(const short8*)(aB01 + 3 * 2048);
        short8 A3_10 = *(const short8*)(aB10 + 3 * 2048);
        short8 A3_11 = *(const short8*)(aB11 + 3 * 2048);

#pragma unroll 1
        for (int ib = 0; ib < 8; ++ib) {
            const int i = ib * 4;
            A_STEP(A0_00, A0_01, A0_10, A0_11, i + 0)
            A_STEP(A1_00, A1_01, A1_10, A1_11, i + 1)
            A_STEP(A2_00, A2_01, A2_10, A2_11, i + 2)
            A_STEP(A3_00, A3_01, A3_10, A3_11, i + 3)
        }
    }

    // store bf16 partial in [z][b][c]: per (tm,tn) lane owns 4 c-consecutive
    unsigned short* pb = Pb + (long)zi * (4096L * 512);
#pragma unroll
    for (int tm = 0; tm < 2; ++tm)
#pragma unroll
        for (int tn = 0; tn < 8; ++tn) {
            int b = bBase + tn * 16 + n16;
            int cb = (c16base + tm) * 16 + quad * 4;
            union { unsigned short s[4]; uint2 u; } pk;
#pragma unroll
            for (int r = 0; r < 4; ++r) pk.s[r] = f2bf(acc[tm][tn][r]);
            *(uint2*)(pb + (long)b * 512 + cb) = pk.u;
        }
}

// ---------------------------------------------------------------------------
// tail: h[b][c] = relu(128*sum_z Pb[z][b][c] + b1[c]) (bf16, LDS), then
// out[b][o] = h @ W2T + b2. 256 thr = 4 waves; b-tile 16 (grid 256 blocks);
// each wave owns 64 o columns.
__global__ __launch_bounds__(256) void tail_kernel(
    const unsigned short* __restrict__ Pb,     // [4][4096][512] bf16
    const float* __restrict__ b1,              // [512]
    const unsigned short* __restrict__ W2T,    // [256][512] bf16
    const float* __restrict__ b2,              // [256]
    float* __restrict__ out) {                 // [4096][256]
    __shared__ unsigned short hL[16][516];
    __shared__ float b1s[512];
    const int tid = threadIdx.x;
    const int b0 = blockIdx.x * 16;
    b1s[tid] = b1[tid];
    b1s[tid + 256] = b1[tid + 256];
    __syncthreads();

    const unsigned int* Pu = (const unsigned int*)Pb;   // 2 bf16 per uint
#pragma unroll 4
    for (int idx = tid; idx < 16 * 256; idx += 256) {
        int bL = idx >> 8;                      // 0..15
        int cu = idx & 255;                     // uint index; c = 2*cu
        float s0 = 0.f, s1 = 0.f;
#pragma unroll
        for (int z = 0; z < 4; ++z) {
            unsigned int u = Pu[((long)z * 4096 + b0 + bL) * 256 + cu];
            s0 += bf2f((unsigned short)(u & 0xffff));
            s1 += bf2f((unsigned short)(u >> 16));
        }
        int c = cu * 2;
        float v0 = fmaxf(fmaf(128.f, s0, b1s[c]), 0.f);
        float v1 = fmaxf(fmaf(128.f, s1, b1s[c + 1]), 0.f);
        unsigned int pk = (unsigned int)f2bf(v0) | ((unsigned int)f2bf(v1) << 16);
        *(unsigned int*)&hL[bL][c] = pk;
    }
    __syncthreads();

    const int w = tid >> 6, lane = tid & 63;
    const int n16 = lane & 15, quad = lane >> 4;
    const int o0 = w * 64;
    floatx4 acc[4];
#pragma unroll
    for (int tn = 0; tn < 4; ++tn) acc[tn] = (floatx4){0.f, 0.f, 0.f, 0.f};

#pragma unroll 4
    for (int ks = 0; ks < 16; ++ks) {
        short8 Af, Bf[4];
        {
            const unsigned short* p = &hL[n16][ks * 32 + quad * 8];
            union { uint2 u[2]; short8 s; } cvt;
            cvt.u[0] = *(const uint2*)p;
            cvt.u[1] = *(const uint2*)(p + 4);
            Af = cvt.s;
        }
#pragma unroll
        for (int tn = 0; tn < 4; ++tn)
            Bf[tn] = *(const short8*)(W2T + (long)(o0 + tn * 16 + n16) * 512
                                      + ks * 32 + quad * 8);
#pragma unroll
        for (int tn = 0; tn < 4; ++tn)
            acc[tn] = __builtin_amdgcn_mfma_f32_16x16x32_bf16(
                Af, Bf[tn], acc[tn], 0, 0, 0);
    }
#pragma unroll
    for (int tn = 0; tn < 4; ++tn) {
        float bias = b2[o0 + tn * 16 + n16];
#pragma unroll
        for (int r = 0; r < 4; ++r)
            out[(long)(b0 + quad * 4 + r) * 256
                + o0 + tn * 16 + n16] = acc[tn][r] + bias;
    }
}

extern "C" void kernel_launch(void* const* d_in, const int* in_sizes, int n_in,
                              void* d_out, int out_size, void* d_ws, size_t ws_size,
                              hipStream_t stream) {
    const float* x  = (const float*)d_in[0];   // [4096,128]
    const float* W1 = (const float*)d_in[1];   // [16384,512]
    const float* b1 = (const float*)d_in[2];   // [512]
    const float* W2 = (const float*)d_in[3];   // [512,256]
    const float* b2 = (const float*)d_in[4];   // [256]
    float* out = (float*)d_out;                // [4096,256]

    char* ws = (char*)d_ws;
    unsigned short* W1Tp = (unsigned short*)(ws);                 // 16.78 MB
    unsigned short* W2T  = (unsigned short*)(ws + 16777216);      // 0.26 MB
    unsigned short* Pb   = (unsigned short*)(ws + 16777216 + 262144); // 16.78 MB bf16

    pack_w1_kernel<<<dim3(256, 8), 256, 0, stream>>>(W1, W1Tp);
    transpose_cast_kernel<<<dim3(8, 4), 256, 0, stream>>>(W2, W2T, 512, 256);
    gemm1_kernel<<<dim3(512), 256, 0, stream>>>(x, W1Tp, Pb);
    tail_kernel<<<dim3(256), 256, 0, stream>>>(Pb, b1, W2T, b2, out);
}